// Round 2
// baseline (653.864 us; speedup 1.0000x reference)
//
#include <hip/hip_runtime.h>
#include <hip/hip_bf16.h>

// MHA: B=2048, N=144, H=4, d=32. qkv [B,144,384] fp32, mask [1,4,144,144] fp32,
// out [B,144,128] fp32. One block per (b,h), 256 thr. bf16 MFMA 16x16x32.
// LDS 40704 B -> 4 blocks/CU (16 waves/CU). Mask prescaled by log2e into ws.

using short8 = __attribute__((ext_vector_type(8))) short;
using f32x4  = __attribute__((ext_vector_type(4))) float;

#define SEQ   144
#define NH    4
#define HD    32
#define C3    384
#define OC    128

#define KSTR  40    // 80 B rows: 16B-aligned, 2-way banks (free)
#define VSTR  152   // 304 B rows: 16B-aligned, 2-way banks
#define PSTR  152

#define LOG2E 1.4426950408889634f
#define SCALE 0.17677669529663687f

__device__ __forceinline__ unsigned short f2bf(float f) {
  unsigned int u = __float_as_uint(f);
  u += 0x7fffu + ((u >> 16) & 1u);
  return (unsigned short)(u >> 16);
}
__device__ __forceinline__ unsigned int pkbf(float a, float b) {
  __hip_bfloat162 h = __float22bfloat162_rn(make_float2(a, b));
  union { __hip_bfloat162 h2; unsigned int u; } cv; cv.h2 = h;
  return cv.u;
}

__global__ void mask_prep(const float* __restrict__ mask, float* __restrict__ o) {
  int i = blockIdx.x * 256 + threadIdx.x;   // 4*144*144 = 82944 = 324*256
  o[i] = mask[i] * LOG2E;
}

__global__ __launch_bounds__(256, 4)
void attn_kernel(const float* __restrict__ qkv,
                 const float* __restrict__ maskS,   // pre-scaled by log2e
                 float* __restrict__ out)
{
  __shared__ __align__(16) unsigned short sP [4 * 16 * PSTR];  // 19456 B
  __shared__ __align__(16) unsigned short sVT[HD * VSTR];      //  9728 B
  __shared__ __align__(16) unsigned short sK [SEQ * KSTR];     // 11520 B

  const int tid = threadIdx.x;
  const int bid = blockIdx.x;
  const int b = bid >> 2;
  const int h = bid & 3;

  const float* qbase = qkv + (size_t)b * (SEQ * C3) + h * HD;
  const float* kbase = qbase + NH * HD;
  const float* vbase = qbase + 2 * NH * HD;

  const int lane = tid & 63;
  const int wv   = tid >> 6;
  const int m    = lane & 15;
  const int quad = lane >> 4;

  // ---- pre-load Q for owned strips (before barrier, hides HBM latency) ----
  const float qs = SCALE * LOG2E;
  float4 q0[3], q1[3];
#pragma unroll
  for (int i = 0; i < 3; ++i) {
    int s = wv + 4 * i;
    if (s < 9) {
      const float* qrow = qbase + (size_t)(s * 16 + m) * C3 + quad * 8;
      q0[i] = *(const float4*)(qrow);
      q1[i] = *(const float4*)(qrow + 4);
    }
  }

  // ---- stage K [144][KSTR] and V^T [32][VSTR] as bf16, float4 loads ----
  const int nr = tid >> 3;          // 0..31
  const int d4 = (tid & 7) * 4;     // 0..28
#pragma unroll
  for (int p = 0; p < 4; ++p) {
    int n = p * 32 + nr;
    float4 k4 = *(const float4*)(kbase + (size_t)n * C3 + d4);
    unsigned long long w = (unsigned long long)pkbf(k4.x, k4.y)
                         | ((unsigned long long)pkbf(k4.z, k4.w) << 32);
    *(unsigned long long*)&sK[n * KSTR + d4] = w;
    float4 v4 = *(const float4*)(vbase + (size_t)n * C3 + d4);
    sVT[(d4 + 0) * VSTR + n] = f2bf(v4.x);
    sVT[(d4 + 1) * VSTR + n] = f2bf(v4.y);
    sVT[(d4 + 2) * VSTR + n] = f2bf(v4.z);
    sVT[(d4 + 3) * VSTR + n] = f2bf(v4.w);
  }
  if (nr < 16) {                     // rows 128..143
    int n = 128 + nr;
    float4 k4 = *(const float4*)(kbase + (size_t)n * C3 + d4);
    unsigned long long w = (unsigned long long)pkbf(k4.x, k4.y)
                         | ((unsigned long long)pkbf(k4.z, k4.w) << 32);
    *(unsigned long long*)&sK[n * KSTR + d4] = w;
    float4 v4 = *(const float4*)(vbase + (size_t)n * C3 + d4);
    sVT[(d4 + 0) * VSTR + n] = f2bf(v4.x);
    sVT[(d4 + 1) * VSTR + n] = f2bf(v4.y);
    sVT[(d4 + 2) * VSTR + n] = f2bf(v4.z);
    sVT[(d4 + 3) * VSTR + n] = f2bf(v4.w);
  }
  __syncthreads();

  unsigned short* pbuf = sP + wv * (16 * PSTR);
  const float* mb = maskS + (size_t)h * SEQ * SEQ;

#pragma unroll
  for (int i = 0; i < 3; ++i) {
    int s = wv + 4 * i;
    if (s < 9) {
      // ---- Q fragment ----
      union { short8 s8; unsigned int u[4]; } af;
      af.u[0] = pkbf(q0[i].x * qs, q0[i].y * qs);
      af.u[1] = pkbf(q0[i].z * qs, q0[i].w * qs);
      af.u[2] = pkbf(q1[i].x * qs, q1[i].y * qs);
      af.u[3] = pkbf(q1[i].z * qs, q1[i].w * qs);

      // ---- S = QK^T with mask*log2e as C-init ----
      float S[9][4];
      const float* mrow0 = mb + (size_t)(s * 16 + quad * 4) * SEQ + m;
#pragma unroll
      for (int nt = 0; nt < 9; ++nt) {
        const float* mr = mrow0 + nt * 16;
        f32x4 c;
        c[0] = mr[0]; c[1] = mr[SEQ]; c[2] = mr[2 * SEQ]; c[3] = mr[3 * SEQ];
        short8 bfrag = *(const short8*)&sK[(nt * 16 + m) * KSTR + quad * 8];
        c = __builtin_amdgcn_mfma_f32_16x16x32_bf16(af.s8, bfrag, c, 0, 0, 0);
        S[nt][0] = c[0]; S[nt][1] = c[1]; S[nt][2] = c[2]; S[nt][3] = c[3];
      }

      // ---- softmax (log2 domain) ----
      float mx[4], l[4];
#pragma unroll
      for (int r = 0; r < 4; ++r) {
        float a = fmaxf(fmaxf(S[0][r], S[1][r]), S[2][r]);
        float bb = fmaxf(fmaxf(S[3][r], S[4][r]), S[5][r]);
        float cc = fmaxf(fmaxf(S[6][r], S[7][r]), S[8][r]);
        float v = fmaxf(fmaxf(a, bb), cc);
        v = fmaxf(v, __shfl_xor(v, 1));
        v = fmaxf(v, __shfl_xor(v, 2));
        v = fmaxf(v, __shfl_xor(v, 4));
        v = fmaxf(v, __shfl_xor(v, 8));
        mx[r] = v; l[r] = 0.f;
      }
#pragma unroll
      for (int nt = 0; nt < 9; ++nt)
#pragma unroll
        for (int r = 0; r < 4; ++r) {
          float p = __builtin_amdgcn_exp2f(S[nt][r] - mx[r]);
          S[nt][r] = p;
          l[r] += p;
        }
#pragma unroll
      for (int r = 0; r < 4; ++r) {
        float v = l[r];
        v += __shfl_xor(v, 1);
        v += __shfl_xor(v, 2);
        v += __shfl_xor(v, 4);
        v += __shfl_xor(v, 8);
        l[r] = v;
      }
      // redistribute: lane (quad,m) needs 1/l of q_row = m
      int src = (m >> 2) * 16 + m;
      float s0 = __shfl(l[0], src), s1 = __shfl(l[1], src);
      float s2 = __shfl(l[2], src), s3 = __shfl(l[3], src);
      float lsel = (m & 2) ? ((m & 1) ? s3 : s2) : ((m & 1) ? s1 : s0);
      float linv = __builtin_amdgcn_rcpf(lsel);

      // ---- P -> LDS (C-layout write; B-operand read) ----
#pragma unroll
      for (int nt = 0; nt < 9; ++nt)
#pragma unroll
        for (int r = 0; r < 4; ++r)
          pbuf[(quad * 4 + r) * PSTR + nt * 16 + m] = f2bf(S[nt][r]);

      // ---- O^T = V^T P^T: A=V^T rows d, B=P rows q_row ----
      f32x4 acc0 = {0.f, 0.f, 0.f, 0.f}, acc1 = {0.f, 0.f, 0.f, 0.f};
#pragma unroll
      for (int kt = 0; kt < 4; ++kt) {
        short8 pa  = *(const short8*)&pbuf[m * PSTR + kt * 32 + quad * 8];
        short8 va0 = *(const short8*)&sVT[(m)      * VSTR + kt * 32 + quad * 8];
        short8 va1 = *(const short8*)&sVT[(16 + m) * VSTR + kt * 32 + quad * 8];
        acc0 = __builtin_amdgcn_mfma_f32_16x16x32_bf16(va0, pa, acc0, 0, 0, 0);
        acc1 = __builtin_amdgcn_mfma_f32_16x16x32_bf16(va1, pa, acc1, 0, 0, 0);
      }
      {  // tail: keys 128..143 in quads 0,1; quads 2,3 zeroed (both operands)
        int off = 128 + (quad & 1) * 8;   // clamped address, always in-row
        short8 z = {0, 0, 0, 0, 0, 0, 0, 0};
        short8 pa  = *(const short8*)&pbuf[m * PSTR + off];
        short8 va0 = *(const short8*)&sVT[(m)      * VSTR + off];
        short8 va1 = *(const short8*)&sVT[(16 + m) * VSTR + off];
        if (quad >= 2) { pa = z; va0 = z; va1 = z; }
        acc0 = __builtin_amdgcn_mfma_f32_16x16x32_bf16(va0, pa, acc0, 0, 0, 0);
        acc1 = __builtin_amdgcn_mfma_f32_16x16x32_bf16(va1, pa, acc1, 0, 0, 0);
      }

      // ---- store: lane holds O[q_row=m][d=quad*4+r (+16)] ----
      float* orow = out + ((size_t)b * SEQ + s * 16 + m) * OC + h * HD + quad * 4;
      float4 o0, o1;
      o0.x = acc0[0] * linv; o0.y = acc0[1] * linv;
      o0.z = acc0[2] * linv; o0.w = acc0[3] * linv;
      o1.x = acc1[0] * linv; o1.y = acc1[1] * linv;
      o1.z = acc1[2] * linv; o1.w = acc1[3] * linv;
      *(float4*)(orow)      = o0;
      *(float4*)(orow + 16) = o1;
    }
  }
}

extern "C" void kernel_launch(void* const* d_in, const int* in_sizes, int n_in,
                              void* d_out, int out_size, void* d_ws, size_t ws_size,
                              hipStream_t stream) {
  const float* qkv  = (const float*)d_in[0];
  const float* mask = (const float*)d_in[1];
  float* out = (float*)d_out;
  float* maskS = (float*)d_ws;
  mask_prep<<<dim3(324), dim3(256), 0, stream>>>(mask, maskS);
  attn_kernel<<<dim3(2048 * NH), dim3(256), 0, stream>>>(qkv, maskS, out);
}